// Round 1
// baseline (29.804 us; speedup 1.0000x reference)
//
#include <hip/hip_runtime.h>

// CountHistogram: B=128, C=4, Q=32, D=2048, NBINS=30
// out[b,c,q,bin] = sum_d [ bin(simmat[b,c,q,d]) == bin ] * (dtoks[b,d]!=-1) * (qtoks[b,q]!=-1)

#define NBINS 30
#define DIM   2048
#define QDIM  32
#define CDIM  4

__global__ __launch_bounds__(256) void CountHistogram_kernel(
    const float* __restrict__ simmat,
    const int*   __restrict__ dtoks,
    const int*   __restrict__ qtoks,
    float*       __restrict__ out)
{
    const int bid  = blockIdx.x;                 // = b*C*Q + c*Q + q (row id)
    const int q    = bid & (QDIM - 1);
    const int b    = bid / (CDIM * QDIM);
    const int tid  = threadIdx.x;
    const int wave = tid >> 6;

    __shared__ int h[4][32];                     // per-wave sub-histograms (30 used, 2 pad)
    if (tid < 128) ((int*)h)[tid] = 0;

    const int qt = qtoks[b * QDIM + q];          // wave-uniform
    __syncthreads();

    if (qt != -1) {
        const float4* sm = (const float4*)(simmat + (size_t)bid * DIM);
        const int4*   dt = (const int4*)(dtoks  + (size_t)b   * DIM);
        #pragma unroll
        for (int ch = 0; ch < 2; ++ch) {
            const int idx = ch * 256 + tid;      // 256 lanes * float4 = 1024 elems/chunk
            const float4 s = sm[idx];
            const int4   t = dt[idx];
            // bit-exact replication of ((x + 1.00001f) / 2.0f) * 29.0f, trunc-to-int
            int b0 = (int)((s.x + 1.00001f) / 2.0f * 29.0f);
            int b1 = (int)((s.y + 1.00001f) / 2.0f * 29.0f);
            int b2 = (int)((s.z + 1.00001f) / 2.0f * 29.0f);
            int b3 = (int)((s.w + 1.00001f) / 2.0f * 29.0f);
            if (t.x != -1) atomicAdd(&h[wave][b0], 1);
            if (t.y != -1) atomicAdd(&h[wave][b1], 1);
            if (t.z != -1) atomicAdd(&h[wave][b2], 1);
            if (t.w != -1) atomicAdd(&h[wave][b3], 1);
        }
    }
    __syncthreads();

    if (tid < NBINS) {
        out[(size_t)bid * NBINS + tid] =
            (float)(h[0][tid] + h[1][tid] + h[2][tid] + h[3][tid]);
    }
}

extern "C" void kernel_launch(void* const* d_in, const int* in_sizes, int n_in,
                              void* d_out, int out_size, void* d_ws, size_t ws_size,
                              hipStream_t stream) {
    const float* simmat = (const float*)d_in[0];
    // d_in[1] = dlens (unused by the reference)
    const int*   dtoks  = (const int*)d_in[2];
    const int*   qtoks  = (const int*)d_in[3];
    float*       out    = (float*)d_out;

    const int nrows = 128 * CDIM * QDIM;         // B*C*Q = 16384
    CountHistogram_kernel<<<nrows, 256, 0, stream>>>(simmat, dtoks, qtoks, out);
}